// Round 1
// baseline (173.958 us; speedup 1.0000x reference)
//
#include <hip/hip_runtime.h>

// AnchorTarget (pysot) for b=128, G=64, SCORE=25, A=5, STRIDE=8.
// Outputs concatenated as float32: cls(128,5,25,25) | bt(128,4,5,25,25) |
// bw(128,5,25,25) | max_ov(128,3125). Total 2,800,000 floats.
//
// Round 7: 2 dispatches.
//   K1': gtmax via separable factorization. For a fixed anchor shape,
//        aarea is one of 5 constants, so union=(aarea+garea)-inter is
//        monotone-decreasing in inter and IoU is monotone-increasing.
//        inter = clipX(col)*clipY(row) is separable: grid max =
//        max(clipX)*max(clipY). Bit-exact vs ref's max-of-rounded-divs by
//        monotone rounding. 1 wave per (b,g), no anchor loads (corners are
//        exact small integers), 5 divisions per (b,g). Also zeroes the
//        poscnt/arrival counters.
//   K2': per-anchor row (grid 13x128, 26 waves/CU) unchanged compute, plus
//        fused K3 via last-arriving-block election per batch: release
//        threadfence + agent atomic ticket; elected block re-reads its cls
//        row (agent-scope loads), runs caps scan, writes cls, then spins on
//        batch-127's arrival counter for the final poscnt before writing bw.
// keep-test float equality protected by contract(off) in shared iou_f.

namespace {
constexpr int B_   = 128;
constexpr int N_   = 3125;   // 25*25*5
constexpr int G_   = 64;
constexpr int A_   = 5;
constexpr int S_   = 25;
constexpr int POSN = 16;
constexpr int TOTN = 64;

constexpr int CLS_OFF = 0;
constexpr int BT_OFF  = B_ * A_ * S_ * S_;              // 400000
constexpr int BW_OFF  = BT_OFF + B_ * 4 * A_ * S_ * S_; // 2000000
constexpr int MO_OFF  = BW_OFF + B_ * A_ * S_ * S_;     // 2400000
}

__device__ __forceinline__ float area_f(float x0, float y0, float x1, float y1) {
#pragma clang fp contract(off)
  return ((x1 - x0) + 1.0f) * ((y1 - y0) + 1.0f);
}

__device__ __forceinline__ float iou_f(float a0, float a1, float a2, float a3,
                                       float aarea, float g0, float g1,
                                       float g2, float g3, float garea) {
#pragma clang fp contract(off)
  // exactly mirrors numpy op order: ((min-max)+1), clip, mul, (a+g)-inter, div
  float ix = (fminf(a2, g2) - fmaxf(a0, g0)) + 1.0f;
  float iy = (fminf(a3, g3) - fmaxf(a1, g1)) + 1.0f;
  ix = fmaxf(ix, 0.0f);
  iy = fmaxf(iy, 0.0f);
  float inter = ix * iy;
  return inter / ((aarea + garea) - inter);
}

// ---- K1': gtmax[b][g] via separable per-shape max-inter -------------------
// 1 wave per (b,g): lanes 0..24 evaluate clipped X-extents per column,
// lanes 32..56 clipped Y-extents per row; half-wave max-reduce; product;
// 5 divisions. Block 0 also zeroes arr[0..128] (poscnt + arrival counters).
__global__ __launch_bounds__(256) void k1_gtmax(
    const float* __restrict__ gt,       // (128,64,4)
    float* __restrict__ gtmax,          // (128,64)
    int* __restrict__ arr) {            // [0]=poscnt, [1..128]=arrivals
#pragma clang fp contract(off)
  const int t = threadIdx.x;
  if (blockIdx.x == 0 && t < 1 + B_) arr[t] = 0;

  const int lane = t & 63;
  const int pair = blockIdx.x * 4 + (t >> 6);  // 0..8191
  const int b = pair >> 6;
  const int g = pair & 63;

  const float4 gg = ((const float4*)gt)[b * G_ + g];
  const float garea = area_f(gg.x, gg.y, gg.z, gg.w);

  const int half = lane >> 5;         // 0: x-axis (cols), 1: y-axis (rows)
  const int p = lane & 31;            // grid index, valid for p<25
  const float c = 31.0f + 8.0f * (float)p;  // center = ori(31) + 8*i, exact
  const float Glo = half ? gg.y : gg.x;
  const float Ghi = half ? gg.w : gg.z;
  const bool valid = p < S_;

  // shapes in ratio order (0.33,0.5,1,2,3): (w,h) = (104,32),(88,40),
  // (64,64),(40,80),(32,96); half-sizes and (w+1)*(h+1) exact.
  const float HW[A_] = {52.f, 44.f, 32.f, 20.f, 16.f};
  const float HH[A_] = {16.f, 20.f, 32.f, 40.f, 48.f};
  const float AA[A_] = {3465.f, 3649.f, 4225.f, 3321.f, 3201.f};

  float m = 0.0f;
#pragma unroll
  for (int s = 0; s < A_; ++s) {
    const float H = half ? HH[s] : HW[s];
    // mirrors ref op order: (min(a_hi,g_hi) - max(a_lo,g_lo)) + 1, clip 0
    float v = (fminf(c + H, Ghi) - fmaxf(c - H, Glo)) + 1.0f;
    v = fmaxf(v, 0.0f);
    if (!valid) v = 0.0f;
#pragma unroll
    for (int off = 1; off < 32; off <<= 1)
      v = fmaxf(v, __shfl_xor(v, off, 64));   // max within 32-lane half
    const float other = __shfl_xor(v, 32, 64);
    const float inter = v * other;            // maxX * maxY (commutative)
    const float uni = (AA[s] + garea) - inter;
    m = fmaxf(m, inter / uni);
  }
  if (lane == 0) gtmax[pair] = m;
}

// ---- K2': per-anchor row + fused caps/cls/bw via last-block election ------
__global__ __launch_bounds__(256) void k2_fused(
    const float* __restrict__ gt, const float* __restrict__ anchors,
    const float* __restrict__ gtmax, float* __restrict__ out,
    int* __restrict__ cls0, int* __restrict__ arr) {
#pragma clang fp contract(off)
  const int b = blockIdx.y;
  const int t = threadIdx.x;
  const int n = blockIdx.x * 256 + t;

  __shared__ float s_gt[G_ * 4];
  __shared__ float s_garea[G_];
  __shared__ float s_gtmax[G_];
  __shared__ int   s_pc;
  __shared__ int   s_ticket;
  __shared__ float s_inv;
  __shared__ int   s_c[N_];
  __shared__ int   s_p[256];
  __shared__ int   s_n[256];

  if (t == 0) s_pc = 0;
  s_gt[t] = gt[b * G_ * 4 + t];  // 256 floats == whole gt row
  __syncthreads();
  if (t < G_) {
    s_garea[t] =
        area_f(s_gt[t * 4 + 0], s_gt[t * 4 + 1], s_gt[t * 4 + 2], s_gt[t * 4 + 3]);
    const float v = gtmax[b * G_ + t];
    s_gtmax[t] = (v == 0.0f) ? 1e-5f : v;
  }
  __syncthreads();

  if (n < N_) {
    const float4 aa = ((const float4*)anchors)[n];
    const float aw = (aa.z - aa.x) + 1.0f;
    const float ah = (aa.w - aa.y) + 1.0f;
    const float aarea = aw * ah;  // same op order as area_f

    float best = -1.0f;
    int barg = 0;
    int keep = 0;
#pragma unroll 8
    for (int g = 0; g < G_; ++g) {
      const float4 gg = *(const float4*)&s_gt[g * 4];  // LDS broadcast
      const float v = iou_f(aa.x, aa.y, aa.z, aa.w, aarea,
                            gg.x, gg.y, gg.z, gg.w, s_garea[g]);
      if (v > best) { best = v; barg = g; }  // first-occurrence argmax
      keep |= (v == s_gtmax[g]);             // bit-exact vs K1'
    }

    int cc = -1;
    if (best >= 0.6f) cc = 1;
    if (best <= 0.3f) cc = 0;
    if (keep) cc = 1;
    // agent-scope store: visible to the elected block cross-XCD
    __hip_atomic_store(&cls0[b * N_ + n], cc, __ATOMIC_RELAXED,
                       __HIP_MEMORY_SCOPE_AGENT);
    if (b == B_ - 1 && cc == 1) atomicAdd(&s_pc, 1);

    const float m0 = s_gt[barg * 4 + 0], m1 = s_gt[barg * 4 + 1];
    const float m2 = s_gt[barg * 4 + 2], m3 = s_gt[barg * 4 + 3];
    const float gw = (m2 - m0) + 1.0f;
    const float gh = (m3 - m1) + 1.0f;
    const float acx = aa.x + 0.5f * aw;
    const float acy = aa.y + 0.5f * ah;
    const float gcx = m0 + 0.5f * gw;
    const float gcy = m1 + 0.5f * gh;
    const float dx = (gcx - acx) / aw;
    const float dy = (gcy - acy) / ah;
    const float dw = logf(gw / aw);
    const float dh = logf(gh / ah);

    // layout: n = (y*25 + x)*5 + a
    const int a = n % A_;
    const int rem = n / A_;
    const int x = rem % S_;
    const int y = rem / S_;
    const int spat = y * S_ + x;

    float* __restrict__ out_bt = out + BT_OFF;
    const int btb = ((b * 4 + 0) * A_ + a) * (S_ * S_) + spat;
    out_bt[btb + 0 * A_ * S_ * S_] = dx;
    out_bt[btb + 1 * A_ * S_ * S_] = dy;
    out_bt[btb + 2 * A_ * S_ * S_] = dw;
    out_bt[btb + 3 * A_ * S_ * S_] = dh;

    out[MO_OFF + b * N_ + n] = best;  // coalesced
  }
  __syncthreads();  // drains vmcnt: all global stores of this block issued

  if (t == 0) {
    if (b == B_ - 1 && s_pc > 0) atomicAdd(&arr[0], s_pc);
    __threadfence();  // release: cls0 + poscnt visible before ticket
    s_ticket = atomicAdd(&arr[1 + b], 1);
  }
  __syncthreads();
  if (s_ticket != 12) return;  // uniform: only last-arriving block continues

  // ---- elected: caps scan + cls + bw (former K3) ----
  __threadfence();  // acquire: see the other 12 blocks' cls0 stores
#pragma unroll
  for (int k = 0; k < 13; ++k) {
    const int i = k * 256 + t;
    if (i < N_)
      s_c[i] = __hip_atomic_load(&cls0[b * N_ + i], __ATOMIC_RELAXED,
                                 __HIP_MEMORY_SCOPE_AGENT);
  }
  __syncthreads();

  const int n0 = t * 13;
  int myp = 0, myn = 0;
#pragma unroll
  for (int k = 0; k < 13; ++k) {
    const int nn = n0 + k;
    if (nn < N_) {
      const int cc = s_c[nn];
      myp += (cc == 1);
      myn += (cc == 0);
    }
  }
  s_p[t] = myp;
  s_n[t] = myn;
  __syncthreads();
  for (int off = 1; off < 256; off <<= 1) {
    int vp = 0, vn = 0;
    if (t >= off) { vp = s_p[t - off]; vn = s_n[t - off]; }
    __syncthreads();
    s_p[t] += vp;
    s_n[t] += vn;
    __syncthreads();
  }

  int runp = s_p[t] - myp;  // exclusive prefix
  int runn = s_n[t] - myn;
#pragma unroll
  for (int k = 0; k < 13; ++k) {
    const int nn = n0 + k;
    if (nn >= N_) break;
    int cc = s_c[nn];
    if (cc == 1) {
      if (++runp > POSN) cc = -1;
    } else if (cc == 0) {
      if (++runn > TOTN) cc = -1;
    }
    s_c[nn] = __float_as_int((float)cc);  // own slot, no race
  }
  __syncthreads();

  // cls does not need poscnt: write it before waiting.
#pragma unroll
  for (int k = 0; k < 13; ++k) {
    const int o = k * 256 + t;
    if (o < N_) {
      const int a  = o / 625;
      const int sp = o % 625;
      out[CLS_OFF + b * N_ + o] = __int_as_float(s_c[sp * 5 + a]);
    }
  }

  // bw needs final poscnt from batch 127's 13 blocks: spin on its arrival
  // counter (device-scope RMW read; bounded as a hang guard).
  if (t == 0) {
    if (b != B_ - 1) {
      int guard = 0;
      while (atomicAdd(&arr[1 + (B_ - 1)], 0) < 13 && guard < 200000) {
        __builtin_amdgcn_s_sleep(8);
        ++guard;
      }
    }
    __threadfence();  // acquire: poscnt adds visible
    const int pc = atomicAdd(&arr[0], 0);
    s_inv = 1.0f / (float)((pc < POSN) ? pc : POSN);
  }
  __syncthreads();

#pragma unroll
  for (int k = 0; k < 13; ++k) {
    const int o = k * 256 + t;
    if (o < N_) {
      const int a  = o / 625;
      const int sp = o % 625;
      const float v = __int_as_float(s_c[sp * 5 + a]);
      out[BW_OFF + b * N_ + o] = (v == 1.0f) ? s_inv : 0.0f;
    }
  }
}

extern "C" void kernel_launch(void* const* d_in, const int* in_sizes, int n_in,
                              void* d_out, int out_size, void* d_ws,
                              size_t ws_size, hipStream_t stream) {
  const float* gt = (const float*)d_in[0];       // (128,64,4)
  const float* anchors = (const float*)d_in[1];  // (3125,4)
  float* out = (float*)d_out;
  int* arr = (int*)d_ws;                         // [0]=poscnt, [1..128]=arrivals
  float* gtmax = (float*)d_ws + 256;             // 8192 floats
  int* cls0 = (int*)d_ws + 256 + B_ * G_;        // 400000 ints

  // Stream ordering: K1' zeroes arr & fills gtmax; K2' consumes gtmax,
  // produces everything else (caps scan runs in each batch's last-arriving
  // block). No memsets needed.
  k1_gtmax<<<2048, 256, 0, stream>>>(gt, gtmax, arr);
  k2_fused<<<dim3(13, B_), 256, 0, stream>>>(gt, anchors, gtmax, out, cls0,
                                             arr);
}

// Round 2
// 96.208 us; speedup vs baseline: 1.8081x; 1.8081x over previous
//
#include <hip/hip_runtime.h>

// AnchorTarget (pysot) for b=128, G=64, SCORE=25, A=5, STRIDE=8.
// Outputs concatenated as float32: cls(128,5,25,25) | bt(128,4,5,25,25) |
// bw(128,5,25,25) | max_ov(128,3125). Total 2,800,000 floats.
//
// Round 8: 2 dispatches, no cross-block sync tricks (round-7's in-kernel
// election/spin was a 130us pathology: cross-XCD fences + one-cacheline RMW
// contention; dispatch-boundary coherence is cheaper).
//   K2: per-anchor row (grid 13x128, 256 thr). PROLOGUE computes the
//       batch's 64 gtmax values in-LDS via the separable factorization
//       (correctness-proven in round 7): for a fixed anchor shape, aarea is
//       constant, union=(aarea+garea)-inter is monotone-decreasing in inter,
//       so IoU is monotone-increasing and max-over-grid factorizes:
//       max inter = max(clipX)*max(clipY). Bit-exact vs ref's
//       max-of-rounded-divisions by monotone rounding (RN is monotone, all
//       anchor corners are exact small integers). Kills the old K1 dispatch
//       (25.6M brute-force IoUs) entirely.
//       b==127 blocks write pre-cap positive counts to pos_part[13]
//       unconditionally (plain stores, poison-safe, no zeroing needed).
//   K3: caps scan + cls + bw, LDS-staged coalesced IO (verified round-6
//       version; reads pos_part[0..12] instead of a single atomic counter).
// keep-test float equality protected by contract(off) in shared iou_f.

namespace {
constexpr int B_   = 128;
constexpr int N_   = 3125;   // 25*25*5
constexpr int G_   = 64;
constexpr int A_   = 5;
constexpr int S_   = 25;
constexpr int POSN = 16;
constexpr int TOTN = 64;

constexpr int CLS_OFF = 0;
constexpr int BT_OFF  = B_ * A_ * S_ * S_;              // 400000
constexpr int BW_OFF  = BT_OFF + B_ * 4 * A_ * S_ * S_; // 2000000
constexpr int MO_OFF  = BW_OFF + B_ * A_ * S_ * S_;     // 2400000
}

__device__ __forceinline__ float area_f(float x0, float y0, float x1, float y1) {
#pragma clang fp contract(off)
  return ((x1 - x0) + 1.0f) * ((y1 - y0) + 1.0f);
}

__device__ __forceinline__ float iou_f(float a0, float a1, float a2, float a3,
                                       float aarea, float g0, float g1,
                                       float g2, float g3, float garea) {
#pragma clang fp contract(off)
  // exactly mirrors numpy op order: ((min-max)+1), clip, mul, (a+g)-inter, div
  float ix = (fminf(a2, g2) - fmaxf(a0, g0)) + 1.0f;
  float iy = (fminf(a3, g3) - fmaxf(a1, g1)) + 1.0f;
  ix = fmaxf(ix, 0.0f);
  iy = fmaxf(iy, 0.0f);
  float inter = ix * iy;
  return inter / ((aarea + garea) - inter);
}

// ---- K2: gtmax prologue + per-anchor row -> cls0, bt, max_ov, pos_part ----
// Grid (13, 128), 256 thr, 1 anchor per thread.
__global__ __launch_bounds__(256) void k2_main(
    const float* __restrict__ gt,       // (128,64,4)
    const float* __restrict__ anchors,  // (3125,4)
    float* __restrict__ out,
    int* __restrict__ cls0,             // (128,3125) scratch
    int* __restrict__ pos_part) {       // [13] batch-127 partial pos counts
#pragma clang fp contract(off)
  const int b = blockIdx.y;
  const int t = threadIdx.x;
  const int n = blockIdx.x * 256 + t;

  __shared__ float s_gt[G_ * 4];
  __shared__ float s_garea[G_];
  __shared__ float s_gtmax[G_];
  __shared__ float s_ax[G_][2][A_];  // per-(g,axis,shape) max clipped extent
  __shared__ int   s_pc;

  if (t == 0) s_pc = 0;
  s_gt[t] = gt[b * G_ * 4 + t];  // 256 floats == whole gt row
  __syncthreads();

  // prologue part 1: per-(g,axis) separable max extents, 128 threads.
  // shapes in ratio order (0.33,0.5,1,2,3): (w,h)=(104,32),(88,40),(64,64),
  // (40,80),(32,96); half-sizes and (w+1)*(h+1) exact in fp32.
  if (t < 2 * G_) {
    const int g    = t >> 1;
    const int axis = t & 1;  // 0: x (cols), 1: y (rows)
    const float Glo = s_gt[g * 4 + axis];
    const float Ghi = s_gt[g * 4 + 2 + axis];
#pragma unroll
    for (int s = 0; s < A_; ++s) {
      const float HW[A_] = {52.f, 44.f, 32.f, 20.f, 16.f};
      const float HH[A_] = {16.f, 20.f, 32.f, 40.f, 48.f};
      const float H = axis ? HH[s] : HW[s];
      float mx = 0.0f;
#pragma unroll
      for (int p = 0; p < S_; ++p) {
        const float c = 31.0f + 8.0f * (float)p;  // center, exact
        // mirrors ref op order: (min(a_hi,g_hi) - max(a_lo,g_lo)) + 1, clip
        float v = (fminf(c + H, Ghi) - fmaxf(c - H, Glo)) + 1.0f;
        mx = fmaxf(mx, fmaxf(v, 0.0f));
      }
      s_ax[g][axis][s] = mx;
    }
  }
  if (t < G_) {
    s_garea[t] =
        area_f(s_gt[t * 4 + 0], s_gt[t * 4 + 1], s_gt[t * 4 + 2], s_gt[t * 4 + 3]);
  }
  __syncthreads();

  // prologue part 2: combine axes -> gtmax[g] (5 divisions per g).
  if (t < G_) {
    const float AA[A_] = {3465.f, 3649.f, 4225.f, 3321.f, 3201.f};
    const float garea = s_garea[t];
    float m = 0.0f;
#pragma unroll
    for (int s = 0; s < A_; ++s) {
      const float inter = s_ax[t][0][s] * s_ax[t][1][s];  // maxX * maxY
      const float uni = (AA[s] + garea) - inter;
      m = fmaxf(m, inter / uni);
    }
    s_gtmax[t] = (m == 0.0f) ? 1e-5f : m;
  }
  __syncthreads();

  if (n < N_) {
    const float4 aa = ((const float4*)anchors)[n];
    const float aw = (aa.z - aa.x) + 1.0f;
    const float ah = (aa.w - aa.y) + 1.0f;
    const float aarea = aw * ah;  // same op order as area_f

    float best = -1.0f;
    int barg = 0;
    int keep = 0;
#pragma unroll 8
    for (int g = 0; g < G_; ++g) {
      const float4 gg = *(const float4*)&s_gt[g * 4];  // LDS broadcast
      const float v = iou_f(aa.x, aa.y, aa.z, aa.w, aarea,
                            gg.x, gg.y, gg.z, gg.w, s_garea[g]);
      if (v > best) { best = v; barg = g; }  // first-occurrence argmax
      keep |= (v == s_gtmax[g]);             // bit-exact vs prologue
    }

    int cc = -1;
    if (best >= 0.6f) cc = 1;
    if (best <= 0.3f) cc = 0;
    if (keep) cc = 1;
    cls0[b * N_ + n] = cc;  // coalesced
    if (b == B_ - 1 && cc == 1) atomicAdd(&s_pc, 1);

    const float m0 = s_gt[barg * 4 + 0], m1 = s_gt[barg * 4 + 1];
    const float m2 = s_gt[barg * 4 + 2], m3 = s_gt[barg * 4 + 3];
    const float gw = (m2 - m0) + 1.0f;
    const float gh = (m3 - m1) + 1.0f;
    const float acx = aa.x + 0.5f * aw;
    const float acy = aa.y + 0.5f * ah;
    const float gcx = m0 + 0.5f * gw;
    const float gcy = m1 + 0.5f * gh;
    const float dx = (gcx - acx) / aw;
    const float dy = (gcy - acy) / ah;
    const float dw = logf(gw / aw);
    const float dh = logf(gh / ah);

    // layout: n = (y*25 + x)*5 + a
    const int a = n % A_;
    const int rem = n / A_;
    const int x = rem % S_;
    const int y = rem / S_;
    const int spat = y * S_ + x;

    float* __restrict__ out_bt = out + BT_OFF;
    const int btb = ((b * 4 + 0) * A_ + a) * (S_ * S_) + spat;
    out_bt[btb + 0 * A_ * S_ * S_] = dx;
    out_bt[btb + 1 * A_ * S_ * S_] = dy;
    out_bt[btb + 2 * A_ * S_ * S_] = dw;
    out_bt[btb + 3 * A_ * S_ * S_] = dh;

    out[MO_OFF + b * N_ + n] = best;  // coalesced
  }
  __syncthreads();
  // unconditional write (poison-safe, no zeroing dispatch needed)
  if (t == 0 && b == B_ - 1) pos_part[blockIdx.x] = s_pc;
}

// ---- K3: per-batch caps (first 16 pos / first 64 neg) + cls + bw ----------
__global__ __launch_bounds__(256) void k3_caps_bw(
    float* __restrict__ out, const int* __restrict__ cls0,
    const int* __restrict__ pos_part) {
  const int b = blockIdx.x;
  const int t = threadIdx.x;
  __shared__ int s_c[N_];   // cls0 (int), then capped cls (float bits)
  __shared__ int s_p[256];
  __shared__ int s_n[256];
  __shared__ int s_parts[16];

  if (t < 13) s_parts[t] = pos_part[t];
  // coalesced stage-in
#pragma unroll
  for (int k = 0; k < 13; ++k) {
    const int i = k * 256 + t;
    if (i < N_) s_c[i] = cls0[b * N_ + i];
  }
  __syncthreads();

  const int n0 = t * 13;
  int cvals[13];
  int myp = 0, myn = 0;
#pragma unroll
  for (int k = 0; k < 13; ++k) {
    const int n = n0 + k;
    int cc = -1;
    if (n < N_) {
      cc = s_c[n];
      if (cc == 1) ++myp;
      else if (cc == 0) ++myn;
    }
    cvals[k] = cc;
  }
  s_p[t] = myp;
  s_n[t] = myn;
  __syncthreads();
  for (int off = 1; off < 256; off <<= 1) {
    int vp = 0, vn = 0;
    if (t >= off) { vp = s_p[t - off]; vn = s_n[t - off]; }
    __syncthreads();
    s_p[t] += vp;
    s_n[t] += vn;
    __syncthreads();
  }

  int runp = s_p[t] - myp;  // exclusive prefix
  int runn = s_n[t] - myn;
#pragma unroll
  for (int k = 0; k < 13; ++k) {
    const int n = n0 + k;
    if (n >= N_) break;
    int cc = cvals[k];
    if (cc == 1) {
      if (++runp > POSN) cc = -1;
    } else if (cc == 0) {
      if (++runn > TOTN) cc = -1;
    }
    s_c[n] = __float_as_int((float)cc);  // own slot, no race
  }
  __syncthreads();

  // pos_num = min(pre-cap positives of batch 127, 16); bw = cls==1 ? 1/p : 0
  int pc = 0;
#pragma unroll
  for (int k = 0; k < 13; ++k) pc += s_parts[k];
  const float inv = 1.0f / (float)((pc < POSN) ? pc : POSN);

  // coalesced transposed write: o = a*625 + spat, n = spat*5 + a
#pragma unroll
  for (int k = 0; k < 13; ++k) {
    const int o = k * 256 + t;
    if (o < N_) {
      const int a  = o / 625;
      const int sp = o % 625;
      const float v = __int_as_float(s_c[sp * 5 + a]);
      out[CLS_OFF + b * N_ + o] = v;
      out[BW_OFF + b * N_ + o] = (v == 1.0f) ? inv : 0.0f;
    }
  }
}

extern "C" void kernel_launch(void* const* d_in, const int* in_sizes, int n_in,
                              void* d_out, int out_size, void* d_ws,
                              size_t ws_size, hipStream_t stream) {
  const float* gt = (const float*)d_in[0];       // (128,64,4)
  const float* anchors = (const float*)d_in[1];  // (3125,4)
  float* out = (float*)d_out;
  int* pos_part = (int*)d_ws;                    // [13]
  int* cls0 = (int*)d_ws + 64;                   // 400000 ints

  // Stream ordering: K2 produces cls0 + pos_part (+ bt/max_ov direct);
  // K3 consumes them across the dispatch boundary (runtime flush provides
  // coherence). No memsets, no atomics on global, no cross-block sync.
  k2_main<<<dim3(13, B_), 256, 0, stream>>>(gt, anchors, out, cls0, pos_part);
  k3_caps_bw<<<B_, 256, 0, stream>>>(out, cls0, pos_part);
}

// Round 3
// 92.645 us; speedup vs baseline: 1.8777x; 1.0385x over previous
//
#include <hip/hip_runtime.h>

// AnchorTarget (pysot) for b=128, G=64, SCORE=25, A=5, STRIDE=8.
// Outputs concatenated as float32: cls(128,5,25,25) | bt(128,4,5,25,25) |
// bw(128,5,25,25) | max_ov(128,3125). Total 2,800,000 floats.
//
// Round 9: 2 dispatches.
//   K2: per-anchor row (grid 13x128, 256 thr).
//       - gtmax prologue now CLOSED-FORM: overlap(c) is concave piecewise-
//         linear in the anchor center c with plateau centered at the gt
//         midpoint (shape-independent), so the grid max is attained within
//         +-1 grid step of pm = rint((mid-31)/8). Evaluating the identical
//         f32 expression at 5 clamped candidates pm-2..pm+2 is bit-identical
//         to the 25-point scan (RN is monotone => max-of-rounded ==
//         rounded-at-exact-argmax, which is among the candidates).
//       - instead of writing cls0(b,N) for K3 to re-scan, each block emits a
//         compact meta record: {pcnt, ncnt, first-16 pos anchor ids,
//         first-64 neg anchor ids} via wave-ballot ordered compaction
//         (popcount prefix). Blocks cover contiguous n ranges so block order
//         == anchor order.
//   K3: per-batch: 13 metas -> 13-entry prefix -> mark <=80 survivors in an
//       LDS map initialized to -1 -> coalesced transposed cls/bw writes.
//       pos_num read from batch-127's metas. No 3125-wide scan, no cls0.
//       Poison-safe: only meta slots < validated counts are ever read.
// keep-test float equality protected by contract(off) in shared iou_f.

namespace {
constexpr int B_   = 128;
constexpr int N_   = 3125;   // 25*25*5
constexpr int G_   = 64;
constexpr int A_   = 5;
constexpr int S_   = 25;
constexpr int POSN = 16;
constexpr int TOTN = 64;
constexpr int NBLK = 13;     // blocks per batch in K2
constexpr int MS   = 82;     // meta stride: [0]=pcnt [1]=ncnt [2..17]=plist [18..81]=nlist

constexpr int CLS_OFF = 0;
constexpr int BT_OFF  = B_ * A_ * S_ * S_;              // 400000
constexpr int BW_OFF  = BT_OFF + B_ * 4 * A_ * S_ * S_; // 2000000
constexpr int MO_OFF  = BW_OFF + B_ * A_ * S_ * S_;     // 2400000
}

__device__ __forceinline__ float area_f(float x0, float y0, float x1, float y1) {
#pragma clang fp contract(off)
  return ((x1 - x0) + 1.0f) * ((y1 - y0) + 1.0f);
}

__device__ __forceinline__ float iou_f(float a0, float a1, float a2, float a3,
                                       float aarea, float g0, float g1,
                                       float g2, float g3, float garea) {
#pragma clang fp contract(off)
  // exactly mirrors numpy op order: ((min-max)+1), clip, mul, (a+g)-inter, div
  float ix = (fminf(a2, g2) - fmaxf(a0, g0)) + 1.0f;
  float iy = (fminf(a3, g3) - fmaxf(a1, g1)) + 1.0f;
  ix = fmaxf(ix, 0.0f);
  iy = fmaxf(iy, 0.0f);
  float inter = ix * iy;
  return inter / ((aarea + garea) - inter);
}

// ---- K2: gtmax prologue + per-anchor row -> meta, bt, max_ov --------------
// Grid (13, 128), 256 thr, 1 anchor per thread.
__global__ __launch_bounds__(256) void k2_main(
    const float* __restrict__ gt,       // (128,64,4)
    const float* __restrict__ anchors,  // (3125,4)
    float* __restrict__ out,
    int* __restrict__ meta) {           // (128,13,MS)
#pragma clang fp contract(off)
  const int b = blockIdx.y;
  const int t = threadIdx.x;
  const int n = blockIdx.x * 256 + t;

  __shared__ float s_gtd[G_][8];        // x0 y0 x1 y1 garea gtmax pad pad
  __shared__ float s_ax[G_][2][A_];     // per-(g,axis,shape) max clipped extent
  __shared__ int   s_wt[2][4];          // per-wave pos/neg counts

  s_gtd[t >> 2][t & 3] = gt[b * G_ * 4 + t];  // 256 floats == whole gt row
  __syncthreads();

  // prologue: closed-form separable max extents (waves 0-1) + garea (wave 2).
  // shapes in ratio order (0.33,0.5,1,2,3): (w,h)=(104,32),(88,40),(64,64),
  // (40,80),(32,96); half-sizes and (w+1)*(h+1) exact in fp32.
  if (t < 2 * G_) {
    const int g    = t >> 1;
    const int axis = t & 1;  // 0: x (cols), 1: y (rows)
    const float Glo = s_gtd[g][axis];
    const float Ghi = s_gtd[g][2 + axis];
    const float mid = (Glo + Ghi) * 0.5f;   // plateau center, shape-indep
    const int pm = (int)rintf((mid - 31.0f) * 0.125f);
    float cand[5];
#pragma unroll
    for (int d = 0; d < 5; ++d) {
      int p = pm - 2 + d;
      p = p < 0 ? 0 : (p > 24 ? 24 : p);
      cand[d] = 31.0f + 8.0f * (float)p;    // exact integer center
    }
    const float HW[A_] = {52.f, 44.f, 32.f, 20.f, 16.f};
    const float HH[A_] = {16.f, 20.f, 32.f, 40.f, 48.f};
#pragma unroll
    for (int s = 0; s < A_; ++s) {
      const float H = axis ? HH[s] : HW[s];
      float mx = 0.0f;
#pragma unroll
      for (int d = 0; d < 5; ++d) {
        // identical op order to the full scan: (min - max) + 1, clip 0
        const float v = (fminf(cand[d] + H, Ghi) - fmaxf(cand[d] - H, Glo)) + 1.0f;
        mx = fmaxf(mx, fmaxf(v, 0.0f));
      }
      s_ax[g][axis][s] = mx;
    }
  } else if (t < 192) {
    const int g = t - 128;
    s_gtd[g][4] = area_f(s_gtd[g][0], s_gtd[g][1], s_gtd[g][2], s_gtd[g][3]);
  }
  __syncthreads();

  // combine axes -> gtmax[g] (5 divisions per g).
  if (t < G_) {
    const float AA[A_] = {3465.f, 3649.f, 4225.f, 3321.f, 3201.f};
    const float garea = s_gtd[t][4];
    float m = 0.0f;
#pragma unroll
    for (int s = 0; s < A_; ++s) {
      const float inter = s_ax[t][0][s] * s_ax[t][1][s];  // maxX * maxY
      const float uni = (AA[s] + garea) - inter;
      m = fmaxf(m, inter / uni);
    }
    s_gtd[t][5] = (m == 0.0f) ? 1e-5f : m;
  }
  __syncthreads();

  int cc = -2;  // inactive-lane sentinel (not 1, not 0)
  if (n < N_) {
    const float4 aa = ((const float4*)anchors)[n];
    const float aw = (aa.z - aa.x) + 1.0f;
    const float ah = (aa.w - aa.y) + 1.0f;
    const float aarea = aw * ah;  // same op order as area_f

    float best = -1.0f;
    int barg = 0;
    int keep = 0;
#pragma unroll 8
    for (int g = 0; g < G_; ++g) {
      const float4 gg = *(const float4*)&s_gtd[g][0];  // LDS broadcast
      const float2 ge = *(const float2*)&s_gtd[g][4];  // garea, gtmax
      const float v = iou_f(aa.x, aa.y, aa.z, aa.w, aarea,
                            gg.x, gg.y, gg.z, gg.w, ge.x);
      if (v > best) { best = v; barg = g; }  // first-occurrence argmax
      keep |= (v == ge.y);                   // bit-exact vs prologue
    }

    cc = -1;
    if (best >= 0.6f) cc = 1;
    if (best <= 0.3f) cc = 0;
    if (keep) cc = 1;

    const float m0 = s_gtd[barg][0], m1 = s_gtd[barg][1];
    const float m2 = s_gtd[barg][2], m3 = s_gtd[barg][3];
    const float gw = (m2 - m0) + 1.0f;
    const float gh = (m3 - m1) + 1.0f;
    const float acx = aa.x + 0.5f * aw;
    const float acy = aa.y + 0.5f * ah;
    const float gcx = m0 + 0.5f * gw;
    const float gcy = m1 + 0.5f * gh;
    const float dx = (gcx - acx) / aw;
    const float dy = (gcy - acy) / ah;
    const float dw = logf(gw / aw);
    const float dh = logf(gh / ah);

    // layout: n = (y*25 + x)*5 + a
    const int a = n % A_;
    const int rem = n / A_;
    const int x = rem % S_;
    const int y = rem / S_;
    const int spat = y * S_ + x;

    float* __restrict__ out_bt = out + BT_OFF;
    const int btb = ((b * 4 + 0) * A_ + a) * (S_ * S_) + spat;
    out_bt[btb + 0 * A_ * S_ * S_] = dx;
    out_bt[btb + 1 * A_ * S_ * S_] = dy;
    out_bt[btb + 2 * A_ * S_ * S_] = dw;
    out_bt[btb + 3 * A_ * S_ * S_] = dh;

    out[MO_OFF + b * N_ + n] = best;  // coalesced
  }

  // ---- ordered compaction: first-16 pos / first-64 neg ids + counts ----
  const int lane = t & 63;
  const int wv   = t >> 6;
  const int pflag = (cc == 1);
  const int nflag = (cc == 0);
  const unsigned long long bp = __ballot(pflag);
  const unsigned long long bn = __ballot(nflag);
  const unsigned long long ltm = (1ull << lane) - 1ull;
  const int pp = __popcll(bp & ltm);  // pos rank within wave
  const int pn = __popcll(bn & ltm);
  if (lane == 0) {
    s_wt[0][wv] = __popcll(bp);
    s_wt[1][wv] = __popcll(bn);
  }
  __syncthreads();
  int wop = 0, won = 0, totp = 0, totn = 0;
#pragma unroll
  for (int i = 0; i < 4; ++i) {
    const int ap = s_wt[0][i], an = s_wt[1][i];
    if (i < wv) { wop += ap; won += an; }
    totp += ap;
    totn += an;
  }
  const int base = (b * NBLK + blockIdx.x) * MS;
  if (pflag && (wop + pp) < POSN) meta[base + 2 + wop + pp] = n;
  if (nflag && (won + pn) < TOTN) meta[base + 2 + POSN + won + pn] = n;
  if (t == 0) {
    meta[base + 0] = totp;
    meta[base + 1] = totn;
  }
}

// ---- K3: per-batch survivor marking + cls + bw ----------------------------
__global__ __launch_bounds__(256) void k3_caps_bw(
    float* __restrict__ out, const int* __restrict__ meta) {
  const int b = blockIdx.x;
  const int t = threadIdx.x;
  __shared__ int   s_m[NBLK * MS];    // 1066 ints
  __shared__ int   s_cls[N_];         // float bits of final cls
  __shared__ int   s_ppre[NBLK];
  __shared__ int   s_npre[NBLK];
  __shared__ int   s_pc127[NBLK];
  __shared__ float s_inv;

  // stage 13 metas (coalesced); tails beyond valid counts are poison but
  // never dereferenced.
#pragma unroll
  for (int k = 0; k < 5; ++k) {
    const int i = k * 256 + t;
    if (i < NBLK * MS) s_m[i] = meta[b * NBLK * MS + i];
  }
  if (t < NBLK) s_pc127[t] = meta[((B_ - 1) * NBLK + t) * MS];
  // init survivor map to -1.0f bits
#pragma unroll
  for (int k = 0; k < 13; ++k) {
    const int i = k * 256 + t;
    if (i < N_) s_cls[i] = 0xBF800000;  // -1.0f
  }
  __syncthreads();

  if (t == 0) {
    int ap = 0, an = 0, pc = 0;
#pragma unroll
    for (int j = 0; j < NBLK; ++j) {
      s_ppre[j] = ap;
      s_npre[j] = an;
      ap += s_m[j * MS + 0];
      an += s_m[j * MS + 1];
      pc += s_pc127[j];
    }
    s_inv = 1.0f / (float)((pc < POSN) ? pc : POSN);
  }
  __syncthreads();

  // mark positive survivors (first 16 by anchor order)
  if (t < NBLK * POSN) {
    const int j = t >> 4, i = t & 15;
    const int c = s_m[j * MS + 0];
    const int cv = (c < POSN) ? c : POSN;
    if (i < cv && (s_ppre[j] + i) < POSN)
      s_cls[s_m[j * MS + 2 + i]] = 0x3F800000;  // 1.0f
  }
  // mark negative survivors (first 64 by anchor order)
#pragma unroll
  for (int k = 0; k < 4; ++k) {
    const int idx = k * 256 + t;
    if (idx < NBLK * TOTN) {
      const int j = idx >> 6, i = idx & 63;
      const int c = s_m[j * MS + 1];
      const int cv = (c < TOTN) ? c : TOTN;
      if (i < cv && (s_npre[j] + i) < TOTN)
        s_cls[s_m[j * MS + 2 + POSN + i]] = 0;  // 0.0f
    }
  }
  __syncthreads();

  // coalesced transposed write: o = a*625 + spat, n = spat*5 + a
  const float inv = s_inv;
#pragma unroll
  for (int k = 0; k < 13; ++k) {
    const int o = k * 256 + t;
    if (o < N_) {
      const int a  = o / 625;
      const int sp = o % 625;
      const float v = __int_as_float(s_cls[sp * 5 + a]);
      out[CLS_OFF + b * N_ + o] = v;
      out[BW_OFF + b * N_ + o] = (v == 1.0f) ? inv : 0.0f;
    }
  }
}

extern "C" void kernel_launch(void* const* d_in, const int* in_sizes, int n_in,
                              void* d_out, int out_size, void* d_ws,
                              size_t ws_size, hipStream_t stream) {
  const float* gt = (const float*)d_in[0];       // (128,64,4)
  const float* anchors = (const float*)d_in[1];  // (3125,4)
  float* out = (float*)d_out;
  int* meta = (int*)d_ws;                        // 128*13*82 ints = 546 KB

  // Stream ordering: K2 produces meta (+ bt/max_ov direct); K3 consumes it
  // across the dispatch boundary (runtime flush provides coherence).
  // No memsets, no global atomics, no cross-block sync.
  k2_main<<<dim3(NBLK, B_), 256, 0, stream>>>(gt, anchors, out, meta);
  k3_caps_bw<<<B_, 256, 0, stream>>>(out, meta);
}